// Round 19
// baseline (308.331 us; speedup 1.0000x reference)
//
#include <hip/hip_runtime.h>

#define NN 50000
#define EE 500000
#define FD 128
#define HD 64
#define NET 3
#define CSTRIDE 650000   // E + 3N (x4 padding: <=3 pads per node), in u16 elements

#define CVT_BLKS   (NN / 4)                    // 12500: wave-per-row cvt+sim
#define CNT_BLKS   ((NET * EE + 255) / 256)    // 5860: edge counting
#define PREP_BLKS  (CVT_BLKS + CNT_BLKS + 1)   // +1 zero-pad block

__device__ __forceinline__ unsigned short f2bf(float f) {
    union { float f; unsigned int i; } c; c.f = f;
    unsigned int u = c.i;
    return (unsigned short)((u + 0x7fffu + ((u >> 16) & 1u)) >> 16);   // RNE
}
__device__ __forceinline__ float tanh_fast(float x) {
    float e = __expf(2.0f * x);
    return 1.0f - __fdividef(2.0f, e + 1.0f);
}
// lo bf16 of a packed u32 -> f32 (exact)
__device__ __forceinline__ float bflo(unsigned int u) { return __uint_as_float(u << 16); }
// hi bf16 -> f32 APPROX (low mantissa garbage <= 2^-8 rel; below bf16 noise)
__device__ __forceinline__ float bfhiA(unsigned int u) { return __uint_as_float(u); }
// exact hi
__device__ __forceinline__ float bfhiX(unsigned int u) { return __uint_as_float(u & 0xffff0000u); }

// -------- prep: cvt+sim (wave/row) | count | zero pads --------
// R17 lesson: NO low-cardinality atomic targets (1173-ctr histogram -> serial).
__global__ void k_prepcount(const float* __restrict__ feat, unsigned short* __restrict__ featb,
                            unsigned short* __restrict__ h1b,
                            const float* __restrict__ Wm, const float* __restrict__ bm,
                            float* __restrict__ simout,
                            const int* __restrict__ d0, const int* __restrict__ d1,
                            const int* __restrict__ d2, int* __restrict__ cnt) {
    int bid = blockIdx.x;
    if (bid < CVT_BLKS) {
        // one wave per feat row: bf16 convert + fused sim head
        int w    = threadIdx.x >> 6;
        int lane = threadIdx.x & 63;
        int row  = bid * 4 + w;
        const float2 f = *(const float2*)(feat + (size_t)row * FD + lane * 2);
        ushort2 o; o.x = f2bf(f.x); o.y = f2bf(f.y);
        *(ushort2*)(featb + (size_t)row * FD + lane * 2) = o;
        float sp0 = f.x * Wm[(lane * 2) * 2 + 0] + f.y * Wm[(lane * 2 + 1) * 2 + 0];
        float sp1 = f.x * Wm[(lane * 2) * 2 + 1] + f.y * Wm[(lane * 2 + 1) * 2 + 1];
        #pragma unroll
        for (int off = 1; off <= 32; off <<= 1) {
            sp0 += __shfl_xor(sp0, off, 64);
            sp1 += __shfl_xor(sp1, off, 64);
        }
        if (lane == 0) {
            simout[row * 2 + 0] = tanh_fast(sp0 + bm[0]);
            simout[row * 2 + 1] = tanh_fast(sp1 + bm[1]);
        }
    } else if (bid < CVT_BLKS + CNT_BLKS) {
        int e = (bid - CVT_BLKS) * 256 + threadIdx.x;
        if (e < NET * EE) {
            int et = e / EE;
            int i  = e - et * EE;
            const int* d = (et == 0) ? d0 : ((et == 1) ? d1 : d2);
            atomicAdd(&cnt[et * NN + d[i]], 1);
        }
    } else {
        int t = threadIdx.x;
        if (t < 32) *(ushort4*)(featb + (size_t)NN * FD + t * 4) = make_ushort4(0, 0, 0, 0);
        else if (t < 48) {
            int i = t - 32;
            *(ushort4*)(h1b + (size_t)NN * HD + i * 4) = make_ushort4(0, 0, 0, 0);
        }
    }
}

// ---------------- 2-kernel parallel scan over x4-PADDED counts ----------------
__global__ void k_scan1(const int* __restrict__ cnt, int* __restrict__ bsum) {
    int et = blockIdx.x / 50, b = blockIdx.x % 50;
    const int* c = cnt + et * NN + b * 1000;
    __shared__ int sh[256];
    int t = threadIdx.x;
    int s = 0;
    for (int i = t; i < 1000; i += 256) s += (c[i] + 3) & ~3;
    sh[t] = s; __syncthreads();
    for (int off = 128; off > 0; off >>= 1) {
        if (t < off) sh[t] += sh[t + off];
        __syncthreads();
    }
    if (t == 0) bsum[blockIdx.x] = sh[0];
}
// scan3: per-block prefix of bsum inline; local prefix over 1000 counts; writes
// rowptr/cursor/invd + PAD cols. GUARD: t>=250 must not touch memory (R13 crash).
__global__ void k_scan3(const int* __restrict__ cnt, const int* __restrict__ bsum,
                        int* __restrict__ rowptr, int* __restrict__ cursor,
                        unsigned short* __restrict__ col, float* __restrict__ invd) {
    int blk = blockIdx.x;            // 0..149
    int et = blk / 50, b = blk % 50;
    int boff = 0;
    for (int q = 0; q < b; ++q) boff += bsum[et * 50 + q];
    const int* c = cnt + et * NN + b * 1000;
    __shared__ int sh[256];
    int t = threadIdx.x;
    int i0 = t * 4;
    int c4[4] = {0, 0, 0, 0};
    int s = 0;
    if (i0 < 1000) {
        #pragma unroll
        for (int q = 0; q < 4; ++q) { int v = c[i0 + q]; c4[q] = v; s += (v + 3) & ~3; }
    }
    sh[t] = s; __syncthreads();
    for (int off = 1; off < 256; off <<= 1) {
        int add = (t >= off) ? sh[t - off] : 0;
        __syncthreads();
        sh[t] += add;
        __syncthreads();
    }
    int run = boff + sh[t] - s;
    if (i0 < 1000) {
        int* rp = rowptr + et * (NN + 1);
        int* cu = cursor + et * NN;
        unsigned short* cl = col + (size_t)et * CSTRIDE;
        float* iv = invd + et * NN;
        int node0 = b * 1000 + i0;
        #pragma unroll
        for (int q = 0; q < 4; ++q) {
            int node = node0 + q; int v = c4[q]; int pv = (v + 3) & ~3;
            rp[node] = run; cu[node] = run;
            iv[node] = 1.0f / (float)((v > 0) ? v : 1);
            for (int k = v; k < pv; ++k) cl[run + k] = (unsigned short)NN; // pad -> zero row
            run += pv;
        }
        if (b == 49 && t == 249) rp[NN] = run;   // last valid thread holds the total
    }
}

// ---------------- scatter: u16 col (halves dirty bytes vs u32) ----------------
__global__ void k_scatter(const int* __restrict__ s0, const int* __restrict__ d0,
                          const int* __restrict__ s1, const int* __restrict__ d1,
                          const int* __restrict__ s2, const int* __restrict__ d2,
                          int* __restrict__ cursor, unsigned short* __restrict__ col) {
    int t = blockIdx.x * 256 + threadIdx.x;
    if (t >= NET * EE) return;
    int et = t / EE;
    int e  = t - et * EE;
    const int* s = (et == 0) ? s0 : ((et == 1) ? s1 : s2);
    const int* d = (et == 0) ? d0 : ((et == 1) ? d1 : d2);
    int dd = d[e];
    int pos = atomicAdd(&cursor[et * NN + dd], 1);
    col[(size_t)et * CSTRIDE + pos] = (unsigned short)s[e];
}

// ---------------- Layer 0 ----------------
// One wave per node; slot s=lane>>4; 16 lanes x 16B cover a full bf16 row.
// QUAD-ISSUE inner loop: j+=16, 4 unconditional uint4 loads per iteration.
// Invalid edge slots select index NN (zero row) on the ADDRESS -- not value
// masking, because out-of-segment col entries may be poison whose bf16 bits
// decode to NaN (0 x NaN = NaN). Zero-row contributions are exactly 0.
// W0 global lane-coalesced (R11). Plain launch_bounds (R14 spill lesson).

__global__ __launch_bounds__(256) void k_layer0(
    const float* __restrict__ feat, const unsigned short* __restrict__ featb,
    const float* __restrict__ W0, const float* __restrict__ b0, const float* __restrict__ p0,
    const int* __restrict__ rowptr, const unsigned short* __restrict__ col,
    const float* __restrict__ invd,
    unsigned short* __restrict__ h1b) {
    __shared__ float hbuf[4][FD];      // 2 KiB, one row per wave
    int w    = threadIdx.x >> 6;       // 4 nodes per block
    int lane = threadIdx.x & 63;
    int s    = lane >> 4;
    int i    = lane & 15;
    int d8   = i * 8;
    int node = (int)blockIdx.x * 4 + w;     // 50000 % 4 == 0

    const float2 fr = *(const float2*)(feat + (size_t)node * FD + d8 + 2 * s);

    float a0 = 0.f, a1 = 0.f;          // this slot's 2 dims only
    #pragma unroll
    for (int et = 0; et < NET; ++et) {
        const int* rp = rowptr + et * (NN + 1);
        int st = rp[node], t = rp[node + 1];
        const unsigned short* cc = col + (size_t)et * CSTRIDE;
        float x0 = 0.f, x1 = 0.f, x2 = 0.f, x3 = 0.f;
        float x4 = 0.f, x5 = 0.f, x6 = 0.f, x7 = 0.f;
        for (int base = st; base < t; base += 64) {
            int my = cc[base + lane];               // batched u16 index load
            int m = t - base; if (m > 64) m = 64;   // multiple of 4
            for (int j = 0; j < m; j += 16) {
                int eA = __shfl(my, j + s, 64);                              // j < m
                int eB = (j + 4  < m) ? __shfl(my, j + 4  + s, 64) : NN;
                int eC = (j + 8  < m) ? __shfl(my, j + 8  + s, 64) : NN;
                int eD = (j + 12 < m) ? __shfl(my, j + 12 + s, 64) : NN;
                uint4 uA = *(const uint4*)(featb + (size_t)eA * FD + d8);
                uint4 uB = *(const uint4*)(featb + (size_t)eB * FD + d8);
                uint4 uC = *(const uint4*)(featb + (size_t)eC * FD + d8);
                uint4 uD = *(const uint4*)(featb + (size_t)eD * FD + d8);
                x0 += bflo(uA.x); x1 += bfhiA(uA.x); x2 += bflo(uA.y); x3 += bfhiA(uA.y);
                x4 += bflo(uA.z); x5 += bfhiA(uA.z); x6 += bflo(uA.w); x7 += bfhiA(uA.w);
                x0 += bflo(uB.x); x1 += bfhiA(uB.x); x2 += bflo(uB.y); x3 += bfhiA(uB.y);
                x4 += bflo(uB.z); x5 += bfhiA(uB.z); x6 += bflo(uB.w); x7 += bfhiA(uB.w);
                x0 += bflo(uC.x); x1 += bfhiA(uC.x); x2 += bflo(uC.y); x3 += bfhiA(uC.y);
                x4 += bflo(uC.z); x5 += bfhiA(uC.z); x6 += bflo(uC.w); x7 += bfhiA(uC.w);
                x0 += bflo(uD.x); x1 += bfhiA(uD.x); x2 += bflo(uD.y); x3 += bfhiA(uD.y);
                x4 += bflo(uD.z); x5 += bfhiA(uD.z); x6 += bflo(uD.w); x7 += bfhiA(uD.w);
            }
        }
        // reduce over the 4 edge-slots (lane bits 4,5)
        x0 += __shfl_xor(x0, 16, 64); x0 += __shfl_xor(x0, 32, 64);
        x1 += __shfl_xor(x1, 16, 64); x1 += __shfl_xor(x1, 32, 64);
        x2 += __shfl_xor(x2, 16, 64); x2 += __shfl_xor(x2, 32, 64);
        x3 += __shfl_xor(x3, 16, 64); x3 += __shfl_xor(x3, 32, 64);
        x4 += __shfl_xor(x4, 16, 64); x4 += __shfl_xor(x4, 32, 64);
        x5 += __shfl_xor(x5, 16, 64); x5 += __shfl_xor(x5, 32, 64);
        x6 += __shfl_xor(x6, 16, 64); x6 += __shfl_xor(x6, 32, 64);
        x7 += __shfl_xor(x7, 16, 64); x7 += __shfl_xor(x7, 32, 64);
        float v0 = (s & 2) ? ((s & 1) ? x6 : x4) : ((s & 1) ? x2 : x0);
        float v1 = (s & 2) ? ((s & 1) ? x7 : x5) : ((s & 1) ? x3 : x1);
        float inv = invd[et * NN + node];
        float pe = p0[et];
        a0 += pe * tanh_fast(v0 * inv);
        a1 += pe * tanh_fast(v1 * inv);
    }
    float h0v = tanh_fast(a0 + fr.x);
    float h1v = tanh_fast(a1 + fr.y);

    // h @ W0 + b0: distributed h stage, W0 global lane-coalesced.
    *(float2*)&hbuf[w][d8 + 2 * s] = make_float2(h0v, h1v);
    float o = b0[lane];
    #pragma unroll 8
    for (int k4 = 0; k4 < FD; k4 += 4) {
        float4 hv = *(const float4*)&hbuf[w][k4];
        o = fmaf(hv.x, W0[(k4 + 0) * HD + lane], o);
        o = fmaf(hv.y, W0[(k4 + 1) * HD + lane], o);
        o = fmaf(hv.z, W0[(k4 + 2) * HD + lane], o);
        o = fmaf(hv.w, W0[(k4 + 3) * HD + lane], o);
    }
    h1b[(size_t)node * HD + lane] = f2bf(o);
}

// ---------------- Layer 1 ----------------
// Same quad-issue structure; 16 lanes x 8B cover a full 64-dim bf16 row.
__global__ __launch_bounds__(256) void k_layer1(
    const unsigned short* __restrict__ h1b,
    const float* __restrict__ W1, const float* __restrict__ b1,
    const float* __restrict__ p1, const int* __restrict__ rowptr,
    const unsigned short* __restrict__ col, const float* __restrict__ invd,
    float* __restrict__ out) {
    int w    = threadIdx.x >> 6;
    int lane = threadIdx.x & 63;
    int s    = lane >> 4;
    int i    = lane & 15;
    int d4   = i * 4;
    int node = (int)blockIdx.x * 4 + w;

    uint2 hr = *(const uint2*)(h1b + (size_t)node * HD + d4);

    float a = 0.f;                     // this slot's single dim
    #pragma unroll
    for (int et = 0; et < NET; ++et) {
        const int* rp = rowptr + et * (NN + 1);
        int st = rp[node], t = rp[node + 1];
        const unsigned short* cc = col + (size_t)et * CSTRIDE;
        float x0 = 0.f, x1 = 0.f, x2 = 0.f, x3 = 0.f;
        for (int base = st; base < t; base += 64) {
            int my = cc[base + lane];
            int m = t - base; if (m > 64) m = 64;   // multiple of 4
            for (int j = 0; j < m; j += 16) {
                int eA = __shfl(my, j + s, 64);
                int eB = (j + 4  < m) ? __shfl(my, j + 4  + s, 64) : NN;
                int eC = (j + 8  < m) ? __shfl(my, j + 8  + s, 64) : NN;
                int eD = (j + 12 < m) ? __shfl(my, j + 12 + s, 64) : NN;
                uint2 uA = *(const uint2*)(h1b + (size_t)eA * HD + d4);
                uint2 uB = *(const uint2*)(h1b + (size_t)eB * HD + d4);
                uint2 uC = *(const uint2*)(h1b + (size_t)eC * HD + d4);
                uint2 uD = *(const uint2*)(h1b + (size_t)eD * HD + d4);
                x0 += bflo(uA.x); x1 += bfhiA(uA.x); x2 += bflo(uA.y); x3 += bfhiA(uA.y);
                x0 += bflo(uB.x); x1 += bfhiA(uB.x); x2 += bflo(uB.y); x3 += bfhiA(uB.y);
                x0 += bflo(uC.x); x1 += bfhiA(uC.x); x2 += bflo(uC.y); x3 += bfhiA(uC.y);
                x0 += bflo(uD.x); x1 += bfhiA(uD.x); x2 += bflo(uD.y); x3 += bfhiA(uD.y);
            }
        }
        x0 += __shfl_xor(x0, 16, 64); x0 += __shfl_xor(x0, 32, 64);
        x1 += __shfl_xor(x1, 16, 64); x1 += __shfl_xor(x1, 32, 64);
        x2 += __shfl_xor(x2, 16, 64); x2 += __shfl_xor(x2, 32, 64);
        x3 += __shfl_xor(x3, 16, 64); x3 += __shfl_xor(x3, 32, 64);
        float v = (s & 2) ? ((s & 1) ? x3 : x2) : ((s & 1) ? x1 : x0);
        float inv = invd[et * NN + node];
        a += p1[et] * tanh_fast(v * inv);
    }
    float r0 = bflo(hr.x), r1 = bfhiX(hr.x), r2 = bflo(hr.y), r3 = bfhiX(hr.y);
    float r = (s & 2) ? ((s & 1) ? r3 : r2) : ((s & 1) ? r1 : r0);
    float g = tanh_fast(a + r);

    int dim = d4 + s;
    float q0 = g * W1[dim * 2 + 0];
    float q1 = g * W1[dim * 2 + 1];
    #pragma unroll
    for (int off = 1; off <= 32; off <<= 1) {
        q0 += __shfl_xor(q0, off, 64);
        q1 += __shfl_xor(q1, off, 64);
    }
    if (lane == 0) {
        out[node * 2 + 0] = q0 + b1[0];
        out[node * 2 + 1] = q1 + b1[1];
    }
}

// ---------------- launcher ----------------

extern "C" void kernel_launch(void* const* d_in, const int* in_sizes, int n_in,
                              void* d_out, int out_size, void* d_ws, size_t ws_size,
                              hipStream_t stream) {
    const float* feat = (const float*)d_in[0];
    const float* Wm   = (const float*)d_in[1];
    const float* bm   = (const float*)d_in[2];
    const float* W0   = (const float*)d_in[3];
    const float* b0   = (const float*)d_in[4];
    const float* W1   = (const float*)d_in[5];
    const float* b1   = (const float*)d_in[6];
    const float* p0   = (const float*)d_in[7];
    const float* p1   = (const float*)d_in[8];
    const int* src0 = (const int*)d_in[9];
    const int* dst0 = (const int*)d_in[10];
    const int* src1 = (const int*)d_in[11];
    const int* dst1 = (const int*)d_in[12];
    const int* src2 = (const int*)d_in[13];
    const int* dst2 = (const int*)d_in[14];

    char* ws = (char*)d_ws;
    int*            cnt    = (int*)(ws + 0);                  //   600,000 B
    int*            rowptr = (int*)(ws + 600000);             //   600,016 B
    int*            cursor = (int*)(ws + 1200016);            //   600,000 B
    float*          invd   = (float*)(ws + 1800016);          //   600,000 B
    int*            bsum   = (int*)(ws + 2400016);            //       608 B
    unsigned short* col    = (unsigned short*)(ws + 2400624); // 3,900,256 B (u16, +128 pad)
    unsigned short* featb  = (unsigned short*)(ws + 6300880); // 12,800,256 B
    unsigned short* h1b    = (unsigned short*)(ws + 19101136);//  6,400,128 B
    // total ~25.5 MB

    float* out = (float*)d_out;           // [N,2] first
    float* sim = out + (size_t)NN * 2;    // [N,2] second

    hipMemsetAsync(cnt, 0, sizeof(int) * NET * NN, stream);
    k_prepcount<<<PREP_BLKS, 256, 0, stream>>>(feat, featb, h1b, Wm, bm, sim,
                                               dst0, dst1, dst2, cnt);
    k_scan1<<<150, 256, 0, stream>>>(cnt, bsum);
    k_scan3<<<150, 256, 0, stream>>>(cnt, bsum, rowptr, cursor, col, invd);
    k_scatter<<<(NET * EE + 255) / 256, 256, 0, stream>>>(src0, dst0, src1, dst1, src2, dst2,
                                                          cursor, col);
    k_layer0<<<NN / 4, 256, 0, stream>>>(feat, featb, W0, b0, p0,
                                         rowptr, col, invd, h1b);
    k_layer1<<<NN / 4, 256, 0, stream>>>(h1b, W1, b1, p1, rowptr, col, invd, out);
}

// Round 20
// 301.630 us; speedup vs baseline: 1.0222x; 1.0222x over previous
//
#include <hip/hip_runtime.h>

#define NN 50000
#define EE 500000
#define FD 128
#define HD 64
#define NET 3
#define CSTRIDE 650000   // E + 3N (x4 padding: <=3 pads per node), in u16 elements

#define CVT_BLKS   (NN / 4)                    // 12500: wave-per-row cvt+sim
#define CNT_BLKS   ((NET * EE + 255) / 256)    // 5860: edge counting
#define PREP_BLKS  (CVT_BLKS + CNT_BLKS + 1)   // +1 zero-pad block

__device__ __forceinline__ unsigned short f2bf(float f) {
    union { float f; unsigned int i; } c; c.f = f;
    unsigned int u = c.i;
    return (unsigned short)((u + 0x7fffu + ((u >> 16) & 1u)) >> 16);   // RNE
}
__device__ __forceinline__ float tanh_fast(float x) {
    float e = __expf(2.0f * x);
    return 1.0f - __fdividef(2.0f, e + 1.0f);
}
// lo bf16 of a packed u32 -> f32 (exact)
__device__ __forceinline__ float bflo(unsigned int u) { return __uint_as_float(u << 16); }
// hi bf16 -> f32 APPROX (low mantissa garbage <= 2^-8 rel; below bf16 noise)
__device__ __forceinline__ float bfhiA(unsigned int u) { return __uint_as_float(u); }
// exact hi
__device__ __forceinline__ float bfhiX(unsigned int u) { return __uint_as_float(u & 0xffff0000u); }

// -------- prep: cvt+sim (wave/row) | count | zero pads --------
// R17 lesson: NO low-cardinality atomic targets (1173-ctr histogram -> serial).
__global__ void k_prepcount(const float* __restrict__ feat, unsigned short* __restrict__ featb,
                            unsigned short* __restrict__ h1b,
                            const float* __restrict__ Wm, const float* __restrict__ bm,
                            float* __restrict__ simout,
                            const int* __restrict__ d0, const int* __restrict__ d1,
                            const int* __restrict__ d2, int* __restrict__ cnt) {
    int bid = blockIdx.x;
    if (bid < CVT_BLKS) {
        // one wave per feat row: bf16 convert + fused sim head
        int w    = threadIdx.x >> 6;
        int lane = threadIdx.x & 63;
        int row  = bid * 4 + w;
        const float2 f = *(const float2*)(feat + (size_t)row * FD + lane * 2);
        ushort2 o; o.x = f2bf(f.x); o.y = f2bf(f.y);
        *(ushort2*)(featb + (size_t)row * FD + lane * 2) = o;
        float sp0 = f.x * Wm[(lane * 2) * 2 + 0] + f.y * Wm[(lane * 2 + 1) * 2 + 0];
        float sp1 = f.x * Wm[(lane * 2) * 2 + 1] + f.y * Wm[(lane * 2 + 1) * 2 + 1];
        #pragma unroll
        for (int off = 1; off <= 32; off <<= 1) {
            sp0 += __shfl_xor(sp0, off, 64);
            sp1 += __shfl_xor(sp1, off, 64);
        }
        if (lane == 0) {
            simout[row * 2 + 0] = tanh_fast(sp0 + bm[0]);
            simout[row * 2 + 1] = tanh_fast(sp1 + bm[1]);
        }
    } else if (bid < CVT_BLKS + CNT_BLKS) {
        int e = (bid - CVT_BLKS) * 256 + threadIdx.x;
        if (e < NET * EE) {
            int et = e / EE;
            int i  = e - et * EE;
            const int* d = (et == 0) ? d0 : ((et == 1) ? d1 : d2);
            atomicAdd(&cnt[et * NN + d[i]], 1);
        }
    } else {
        int t = threadIdx.x;
        if (t < 32) *(ushort4*)(featb + (size_t)NN * FD + t * 4) = make_ushort4(0, 0, 0, 0);
        else if (t < 48) {
            int i = t - 32;
            *(ushort4*)(h1b + (size_t)NN * HD + i * 4) = make_ushort4(0, 0, 0, 0);
        }
    }
}

// ---------------- 2-kernel parallel scan over x4-PADDED counts ----------------
__global__ void k_scan1(const int* __restrict__ cnt, int* __restrict__ bsum) {
    int et = blockIdx.x / 50, b = blockIdx.x % 50;
    const int* c = cnt + et * NN + b * 1000;
    __shared__ int sh[256];
    int t = threadIdx.x;
    int s = 0;
    for (int i = t; i < 1000; i += 256) s += (c[i] + 3) & ~3;
    sh[t] = s; __syncthreads();
    for (int off = 128; off > 0; off >>= 1) {
        if (t < off) sh[t] += sh[t + off];
        __syncthreads();
    }
    if (t == 0) bsum[blockIdx.x] = sh[0];
}
// scan3: per-block prefix of bsum inline; local prefix over 1000 counts; writes
// rowptr/cursor/invd + PAD cols. GUARD: t>=250 must not touch memory (R13 crash).
__global__ void k_scan3(const int* __restrict__ cnt, const int* __restrict__ bsum,
                        int* __restrict__ rowptr, int* __restrict__ cursor,
                        unsigned short* __restrict__ col, float* __restrict__ invd) {
    int blk = blockIdx.x;            // 0..149
    int et = blk / 50, b = blk % 50;
    int boff = 0;
    for (int q = 0; q < b; ++q) boff += bsum[et * 50 + q];
    const int* c = cnt + et * NN + b * 1000;
    __shared__ int sh[256];
    int t = threadIdx.x;
    int i0 = t * 4;
    int c4[4] = {0, 0, 0, 0};
    int s = 0;
    if (i0 < 1000) {
        #pragma unroll
        for (int q = 0; q < 4; ++q) { int v = c[i0 + q]; c4[q] = v; s += (v + 3) & ~3; }
    }
    sh[t] = s; __syncthreads();
    for (int off = 1; off < 256; off <<= 1) {
        int add = (t >= off) ? sh[t - off] : 0;
        __syncthreads();
        sh[t] += add;
        __syncthreads();
    }
    int run = boff + sh[t] - s;
    if (i0 < 1000) {
        int* rp = rowptr + et * (NN + 1);
        int* cu = cursor + et * NN;
        unsigned short* cl = col + (size_t)et * CSTRIDE;
        float* iv = invd + et * NN;
        int node0 = b * 1000 + i0;
        #pragma unroll
        for (int q = 0; q < 4; ++q) {
            int node = node0 + q; int v = c4[q]; int pv = (v + 3) & ~3;
            rp[node] = run; cu[node] = run;
            iv[node] = 1.0f / (float)((v > 0) ? v : 1);
            for (int k = v; k < pv; ++k) cl[run + k] = (unsigned short)NN; // pad -> zero row
            run += pv;
        }
        if (b == 49 && t == 249) rp[NN] = run;   // last valid thread holds the total
    }
}

// ---------------- scatter: u16 col (halves dirty bytes vs u32) ----------------
__global__ void k_scatter(const int* __restrict__ s0, const int* __restrict__ d0,
                          const int* __restrict__ s1, const int* __restrict__ d1,
                          const int* __restrict__ s2, const int* __restrict__ d2,
                          int* __restrict__ cursor, unsigned short* __restrict__ col) {
    int t = blockIdx.x * 256 + threadIdx.x;
    if (t >= NET * EE) return;
    int et = t / EE;
    int e  = t - et * EE;
    const int* s = (et == 0) ? s0 : ((et == 1) ? s1 : s2);
    const int* d = (et == 0) ? d0 : ((et == 1) ? d1 : d2);
    int dd = d[e];
    int pos = atomicAdd(&cursor[et * NN + dd], 1);
    col[(size_t)et * CSTRIDE + pos] = (unsigned short)s[e];
}

// ---------------- Layer 0 ----------------
// One wave per node; slot s=lane>>4 gathers edge j+s (16 lanes x 16B = full row).
// Slot keeps only its 2 dims after the reduce. W0 global, lane-coalesced (R11).
// Plain launch_bounds (R14: (256,8) forced VGPR 32 -> spills). Dual-issue j+=8
// + 4-edge tail (R19: quad-issue raised VGPR->52, occ 50->39%, -9% -- reverted).
// col is u16 (half the index-batch bytes).

__global__ __launch_bounds__(256) void k_layer0(
    const float* __restrict__ feat, const unsigned short* __restrict__ featb,
    const float* __restrict__ W0, const float* __restrict__ b0, const float* __restrict__ p0,
    const int* __restrict__ rowptr, const unsigned short* __restrict__ col,
    const float* __restrict__ invd,
    unsigned short* __restrict__ h1b) {
    __shared__ float hbuf[4][FD];      // 2 KiB, one row per wave
    int w    = threadIdx.x >> 6;       // 4 nodes per block
    int lane = threadIdx.x & 63;
    int s    = lane >> 4;
    int i    = lane & 15;
    int d8   = i * 8;
    int node = (int)blockIdx.x * 4 + w;     // 50000 % 4 == 0

    const float2 fr = *(const float2*)(feat + (size_t)node * FD + d8 + 2 * s);

    float a0 = 0.f, a1 = 0.f;          // this slot's 2 dims only
    #pragma unroll
    for (int et = 0; et < NET; ++et) {
        const int* rp = rowptr + et * (NN + 1);
        int st = rp[node], t = rp[node + 1];
        const unsigned short* cc = col + (size_t)et * CSTRIDE;
        float x0 = 0.f, x1 = 0.f, x2 = 0.f, x3 = 0.f;
        float x4 = 0.f, x5 = 0.f, x6 = 0.f, x7 = 0.f;
        for (int base = st; base < t; base += 64) {
            int my = cc[base + lane];               // batched u16 index load
            int m = t - base; if (m > 64) m = 64;   // multiple of 4
            int j = 0;
            for (; j + 8 <= m; j += 8) {
                int eA = __shfl(my, j + s, 64);
                int eB = __shfl(my, j + 4 + s, 64);
                uint4 uA = *(const uint4*)(featb + (size_t)eA * FD + d8);
                uint4 uB = *(const uint4*)(featb + (size_t)eB * FD + d8);
                x0 += bflo(uA.x); x1 += bfhiA(uA.x); x2 += bflo(uA.y); x3 += bfhiA(uA.y);
                x4 += bflo(uA.z); x5 += bfhiA(uA.z); x6 += bflo(uA.w); x7 += bfhiA(uA.w);
                x0 += bflo(uB.x); x1 += bfhiA(uB.x); x2 += bflo(uB.y); x3 += bfhiA(uB.y);
                x4 += bflo(uB.z); x5 += bfhiA(uB.z); x6 += bflo(uB.w); x7 += bfhiA(uB.w);
            }
            if (j < m) {                             // 4-edge tail (wave-uniform)
                int eA = __shfl(my, j + s, 64);
                uint4 uA = *(const uint4*)(featb + (size_t)eA * FD + d8);
                x0 += bflo(uA.x); x1 += bfhiA(uA.x); x2 += bflo(uA.y); x3 += bfhiA(uA.y);
                x4 += bflo(uA.z); x5 += bfhiA(uA.z); x6 += bflo(uA.w); x7 += bfhiA(uA.w);
            }
        }
        // reduce over the 4 edge-slots (lane bits 4,5)
        x0 += __shfl_xor(x0, 16, 64); x0 += __shfl_xor(x0, 32, 64);
        x1 += __shfl_xor(x1, 16, 64); x1 += __shfl_xor(x1, 32, 64);
        x2 += __shfl_xor(x2, 16, 64); x2 += __shfl_xor(x2, 32, 64);
        x3 += __shfl_xor(x3, 16, 64); x3 += __shfl_xor(x3, 32, 64);
        x4 += __shfl_xor(x4, 16, 64); x4 += __shfl_xor(x4, 32, 64);
        x5 += __shfl_xor(x5, 16, 64); x5 += __shfl_xor(x5, 32, 64);
        x6 += __shfl_xor(x6, 16, 64); x6 += __shfl_xor(x6, 32, 64);
        x7 += __shfl_xor(x7, 16, 64); x7 += __shfl_xor(x7, 32, 64);
        float v0 = (s & 2) ? ((s & 1) ? x6 : x4) : ((s & 1) ? x2 : x0);
        float v1 = (s & 2) ? ((s & 1) ? x7 : x5) : ((s & 1) ? x3 : x1);
        float inv = invd[et * NN + node];
        float pe = p0[et];
        a0 += pe * tanh_fast(v0 * inv);
        a1 += pe * tanh_fast(v1 * inv);
    }
    float h0v = tanh_fast(a0 + fr.x);
    float h1v = tanh_fast(a1 + fr.y);

    // h @ W0 + b0: distributed h stage, W0 global lane-coalesced.
    *(float2*)&hbuf[w][d8 + 2 * s] = make_float2(h0v, h1v);
    float o = b0[lane];
    #pragma unroll 8
    for (int k4 = 0; k4 < FD; k4 += 4) {
        float4 hv = *(const float4*)&hbuf[w][k4];
        o = fmaf(hv.x, W0[(k4 + 0) * HD + lane], o);
        o = fmaf(hv.y, W0[(k4 + 1) * HD + lane], o);
        o = fmaf(hv.z, W0[(k4 + 2) * HD + lane], o);
        o = fmaf(hv.w, W0[(k4 + 3) * HD + lane], o);
    }
    h1b[(size_t)node * HD + lane] = f2bf(o);
}

// ---------------- Layer 1 ----------------
__global__ __launch_bounds__(256) void k_layer1(
    const unsigned short* __restrict__ h1b,
    const float* __restrict__ W1, const float* __restrict__ b1,
    const float* __restrict__ p1, const int* __restrict__ rowptr,
    const unsigned short* __restrict__ col, const float* __restrict__ invd,
    float* __restrict__ out) {
    int w    = threadIdx.x >> 6;
    int lane = threadIdx.x & 63;
    int s    = lane >> 4;
    int i    = lane & 15;
    int d4   = i * 4;
    int node = (int)blockIdx.x * 4 + w;

    uint2 hr = *(const uint2*)(h1b + (size_t)node * HD + d4);

    float a = 0.f;                     // this slot's single dim
    #pragma unroll
    for (int et = 0; et < NET; ++et) {
        const int* rp = rowptr + et * (NN + 1);
        int st = rp[node], t = rp[node + 1];
        const unsigned short* cc = col + (size_t)et * CSTRIDE;
        float x0 = 0.f, x1 = 0.f, x2 = 0.f, x3 = 0.f;
        for (int base = st; base < t; base += 64) {
            int my = cc[base + lane];
            int m = t - base; if (m > 64) m = 64;   // multiple of 4
            int j = 0;
            for (; j + 8 <= m; j += 8) {
                int eA = __shfl(my, j + s, 64);
                int eB = __shfl(my, j + 4 + s, 64);
                uint2 uA = *(const uint2*)(h1b + (size_t)eA * HD + d4);
                uint2 uB = *(const uint2*)(h1b + (size_t)eB * HD + d4);
                x0 += bflo(uA.x); x1 += bfhiA(uA.x); x2 += bflo(uA.y); x3 += bfhiA(uA.y);
                x0 += bflo(uB.x); x1 += bfhiA(uB.x); x2 += bflo(uB.y); x3 += bfhiA(uB.y);
            }
            if (j < m) {
                int eA = __shfl(my, j + s, 64);
                uint2 uA = *(const uint2*)(h1b + (size_t)eA * HD + d4);
                x0 += bflo(uA.x); x1 += bfhiA(uA.x); x2 += bflo(uA.y); x3 += bfhiA(uA.y);
            }
        }
        x0 += __shfl_xor(x0, 16, 64); x0 += __shfl_xor(x0, 32, 64);
        x1 += __shfl_xor(x1, 16, 64); x1 += __shfl_xor(x1, 32, 64);
        x2 += __shfl_xor(x2, 16, 64); x2 += __shfl_xor(x2, 32, 64);
        x3 += __shfl_xor(x3, 16, 64); x3 += __shfl_xor(x3, 32, 64);
        float v = (s & 2) ? ((s & 1) ? x3 : x2) : ((s & 1) ? x1 : x0);
        float inv = invd[et * NN + node];
        a += p1[et] * tanh_fast(v * inv);
    }
    float r0 = bflo(hr.x), r1 = bfhiX(hr.x), r2 = bflo(hr.y), r3 = bfhiX(hr.y);
    float r = (s & 2) ? ((s & 1) ? r3 : r2) : ((s & 1) ? r1 : r0);
    float g = tanh_fast(a + r);

    int dim = d4 + s;
    float q0 = g * W1[dim * 2 + 0];
    float q1 = g * W1[dim * 2 + 1];
    #pragma unroll
    for (int off = 1; off <= 32; off <<= 1) {
        q0 += __shfl_xor(q0, off, 64);
        q1 += __shfl_xor(q1, off, 64);
    }
    if (lane == 0) {
        out[node * 2 + 0] = q0 + b1[0];
        out[node * 2 + 1] = q1 + b1[1];
    }
}

// ---------------- launcher ----------------

extern "C" void kernel_launch(void* const* d_in, const int* in_sizes, int n_in,
                              void* d_out, int out_size, void* d_ws, size_t ws_size,
                              hipStream_t stream) {
    const float* feat = (const float*)d_in[0];
    const float* Wm   = (const float*)d_in[1];
    const float* bm   = (const float*)d_in[2];
    const float* W0   = (const float*)d_in[3];
    const float* b0   = (const float*)d_in[4];
    const float* W1   = (const float*)d_in[5];
    const float* b1   = (const float*)d_in[6];
    const float* p0   = (const float*)d_in[7];
    const float* p1   = (const float*)d_in[8];
    const int* src0 = (const int*)d_in[9];
    const int* dst0 = (const int*)d_in[10];
    const int* src1 = (const int*)d_in[11];
    const int* dst1 = (const int*)d_in[12];
    const int* src2 = (const int*)d_in[13];
    const int* dst2 = (const int*)d_in[14];

    char* ws = (char*)d_ws;
    int*            cnt    = (int*)(ws + 0);                  //   600,000 B
    int*            rowptr = (int*)(ws + 600000);             //   600,016 B
    int*            cursor = (int*)(ws + 1200016);            //   600,000 B
    float*          invd   = (float*)(ws + 1800016);          //   600,000 B
    int*            bsum   = (int*)(ws + 2400016);            //       608 B
    unsigned short* col    = (unsigned short*)(ws + 2400624); // 3,900,256 B (u16, +128 pad)
    unsigned short* featb  = (unsigned short*)(ws + 6300880); // 12,800,256 B
    unsigned short* h1b    = (unsigned short*)(ws + 19101136);//  6,400,128 B
    // total ~25.5 MB

    float* out = (float*)d_out;           // [N,2] first
    float* sim = out + (size_t)NN * 2;    // [N,2] second

    hipMemsetAsync(cnt, 0, sizeof(int) * NET * NN, stream);
    k_prepcount<<<PREP_BLKS, 256, 0, stream>>>(feat, featb, h1b, Wm, bm, sim,
                                               dst0, dst1, dst2, cnt);
    k_scan1<<<150, 256, 0, stream>>>(cnt, bsum);
    k_scan3<<<150, 256, 0, stream>>>(cnt, bsum, rowptr, cursor, col, invd);
    k_scatter<<<(NET * EE + 255) / 256, 256, 0, stream>>>(src0, dst0, src1, dst1, src2, dst2,
                                                          cursor, col);
    k_layer0<<<NN / 4, 256, 0, stream>>>(feat, featb, W0, b0, p0,
                                         rowptr, col, invd, h1b);
    k_layer1<<<NN / 4, 256, 0, stream>>>(h1b, W1, b1, p1, rowptr, col, invd, out);
}